// Round 1
// baseline (174.217 us; speedup 1.0000x reference)
//
#include <hip/hip_runtime.h>

// Scaled dot-product attention, B=2 S=2048 D=1024 H=16 dh=64, fp32 in/out.
// Flash-attention forward, bf16 MFMA (16x16x32), fp32 accumulate.
// Block = one (b,h) x 128-query tile; 4 waves x 32 queries each.
// S^T = K*Q^T orientation so softmax reduces with 2 shuffles and P packs b64.
// O^T = V^T*P^T with V transposed in LDS so both frags are ds_read_b128.

#define B_ 2
#define S_ 2048
#define D_ 1024
#define H_ 16
#define DH 64
#define M_TILE 128   // queries per block
#define N_TILE 128   // keys per iteration
#define NWAVE 4
#define QW 32        // queries per wave

typedef __bf16 bf16;
typedef __bf16 bf16x4 __attribute__((ext_vector_type(4)));
typedef __bf16 bf16x8 __attribute__((ext_vector_type(8)));
typedef float floatx4 __attribute__((ext_vector_type(4)));

#define K_STRIDE 72    // 64 + 8 pad (bf16) -> 144B rows, 16B aligned, bank-skewed
#define P_STRIDE 136   // 128 + 8 pad
#define V_STRIDE 136
#define P_BYTES (32 * P_STRIDE * 2)      // 8704 per wave
#define A_BYTES (NWAVE * P_BYTES)        // 34816 (aliased with K tile: 18432)
#define V_BYTES (64 * V_STRIDE * 2)      // 17408

__device__ __forceinline__ float fast_exp2(float x) {
#if __has_builtin(__builtin_amdgcn_exp2f)
  return __builtin_amdgcn_exp2f(x);
#else
  return exp2f(x);
#endif
}

__global__ __launch_bounds__(256, 2)
void attn_fwd(const float* __restrict__ Qg, const float* __restrict__ Kg,
              const float* __restrict__ Vg, float* __restrict__ Og) {
  __shared__ __align__(16) unsigned char smem[A_BYTES + V_BYTES];
  bf16* Ksh = (bf16*)smem;                  // [128][K_STRIDE], dead after S^T
  bf16* Psh = (bf16*)smem;                  // [wave][32][P_STRIDE], aliases Ksh
  bf16* Vsh = (bf16*)(smem + A_BYTES);      // [64][V_STRIDE]  = V^T: [feat][key]

  const int tid  = threadIdx.x;
  const int lane = tid & 63;
  const int wave = tid >> 6;
  const int col  = lane & 15;   // n-index of MFMA (query), also m-index of A-frags
  const int quad = lane >> 4;   // 0..3

  const int bid      = blockIdx.x;
  const int head_lin = bid & 31;   // b*16+h : keeps one head's q-tiles on one XCD
  const int qtile    = bid >> 5;   // 0..15
  const int b        = head_lin >> 4;
  const int h        = head_lin & 15;

  // fold softmax scale (1/8) and log2(e) into Q so logits live in exp2 domain
  const float QSCALE = 0.125f * 1.44269504088896340736f;

  // ---- Q fragments (B-operand of S^T = K*Q^T), persistent in registers ----
  // lane holds Q[q = qtile*128 + wave*32 + qt*16 + col][k = ks*32 + quad*8 + j]
  bf16x8 Qf[2][2];
  {
    const int qrow = qtile * M_TILE + wave * QW + col;
#pragma unroll
    for (int qt = 0; qt < 2; ++qt) {
      const float* base = Qg + (size_t)(b * S_ + qrow + qt * 16) * D_ + h * DH + quad * 8;
#pragma unroll
      for (int ks = 0; ks < 2; ++ks) {
        const float4* p = (const float4*)(base + ks * 32);
        float4 x0 = p[0], x1 = p[1];
        bf16x8 f;
        f[0] = (bf16)(x0.x * QSCALE); f[1] = (bf16)(x0.y * QSCALE);
        f[2] = (bf16)(x0.z * QSCALE); f[3] = (bf16)(x0.w * QSCALE);
        f[4] = (bf16)(x1.x * QSCALE); f[5] = (bf16)(x1.y * QSCALE);
        f[6] = (bf16)(x1.z * QSCALE); f[7] = (bf16)(x1.w * QSCALE);
        Qf[qt][ks] = f;
      }
    }
  }

  floatx4 accS[8][2];            // S^T tiles: [key-tile][query-tile]
  floatx4 accO[4][2];            // O^T tiles: [feat-tile][query-tile]
  float m_run[2] = {-1e30f, -1e30f};
  float l_run[2] = {0.f, 0.f};
#pragma unroll
  for (int ft = 0; ft < 4; ++ft)
#pragma unroll
    for (int qt = 0; qt < 2; ++qt) accO[ft][qt] = (floatx4)0.f;

  const float* Kbase = Kg + (size_t)(b * S_) * D_ + h * DH;
  const float* Vbase = Vg + (size_t)(b * S_) * D_ + h * DH;

  for (int it = 0; it < S_ / N_TILE; ++it) {
    const int kb = it * N_TILE;
    __syncthreads();  // everyone done with previous P/V reads (K aliases P)

    // ---- stage K tile -> Ksh[key][feat], coalesced float4 reads ----
#pragma unroll
    for (int i = 0; i < 8; ++i) {
      int id = tid + i * 256;          // 2048 float4 = 128 rows x 16
      int row = id >> 4, f4 = id & 15;
      float4 x = *(const float4*)(Kbase + (size_t)(kb + row) * D_ + f4 * 4);
      bf16x4 y = {(bf16)x.x, (bf16)x.y, (bf16)x.z, (bf16)x.w};
      *(bf16x4*)(Ksh + row * K_STRIDE + f4 * 4) = y;
    }
    // ---- stage V tile transposed -> Vsh[feat][key], b64 LDS writes ----
    {
      const int r0 = (tid >> 3) << 2;  // 4-key group
      const int f0 = (tid & 7) << 3;   // 8-feat group
      float vals[4][8];
#pragma unroll
      for (int rr = 0; rr < 4; ++rr) {
        const float* vp = Vbase + (size_t)(kb + r0 + rr) * D_ + f0;
        float4 a = *(const float4*)vp;
        float4 c = *(const float4*)(vp + 4);
        vals[rr][0] = a.x; vals[rr][1] = a.y; vals[rr][2] = a.z; vals[rr][3] = a.w;
        vals[rr][4] = c.x; vals[rr][5] = c.y; vals[rr][6] = c.z; vals[rr][7] = c.w;
      }
#pragma unroll
      for (int j = 0; j < 8; ++j) {
        bf16x4 y = {(bf16)vals[0][j], (bf16)vals[1][j], (bf16)vals[2][j], (bf16)vals[3][j]};
        *(bf16x4*)(Vsh + (f0 + j) * V_STRIDE + r0) = y;
      }
    }
    __syncthreads();

    // ---- S^T = K * Q^T ----
#pragma unroll
    for (int kt = 0; kt < 8; ++kt) {
      bf16x8 Ka0 = *(bf16x8*)(Ksh + (kt * 16 + col) * K_STRIDE + quad * 8);
      bf16x8 Ka1 = *(bf16x8*)(Ksh + (kt * 16 + col) * K_STRIDE + 32 + quad * 8);
#pragma unroll
      for (int qt = 0; qt < 2; ++qt) {
        floatx4 acc = (floatx4)0.f;
        acc = __builtin_amdgcn_mfma_f32_16x16x32_bf16(Ka0, Qf[qt][0], acc, 0, 0, 0);
        acc = __builtin_amdgcn_mfma_f32_16x16x32_bf16(Ka1, Qf[qt][1], acc, 0, 0, 0);
        accS[kt][qt] = acc;
      }
    }
    __syncthreads();  // all waves done reading Ksh before P overwrites it

    // ---- online softmax (logits already in exp2 domain) ----
#pragma unroll
    for (int qt = 0; qt < 2; ++qt) {
      float mx = accS[0][qt][0];
#pragma unroll
      for (int kt = 0; kt < 8; ++kt)
#pragma unroll
        for (int r = 0; r < 4; ++r) mx = fmaxf(mx, accS[kt][qt][r]);
      mx = fmaxf(mx, __shfl_xor(mx, 16));
      mx = fmaxf(mx, __shfl_xor(mx, 32));
      const float mn = fmaxf(m_run[qt], mx);
      const float al = fast_exp2(m_run[qt] - mn);
      m_run[qt] = mn;
      float rs = 0.f;
#pragma unroll
      for (int kt = 0; kt < 8; ++kt)
#pragma unroll
        for (int r = 0; r < 4; ++r) {
          float p = fast_exp2(accS[kt][qt][r] - mn);
          accS[kt][qt][r] = p;
          rs += p;
        }
      rs += __shfl_xor(rs, 16);
      rs += __shfl_xor(rs, 32);
      l_run[qt] = l_run[qt] * al + rs;
#pragma unroll
      for (int ft = 0; ft < 4; ++ft) accO[ft][qt] *= al;
    }

    // ---- P -> LDS (bf16), 4 consecutive keys packed per b64 write ----
    bf16* Pw = Psh + wave * (32 * P_STRIDE);
#pragma unroll
    for (int kt = 0; kt < 8; ++kt)
#pragma unroll
      for (int qt = 0; qt < 2; ++qt) {
        floatx4 p = accS[kt][qt];
        bf16x4 pk = {(bf16)p[0], (bf16)p[1], (bf16)p[2], (bf16)p[3]};
        *(bf16x4*)(Pw + (qt * 16 + col) * P_STRIDE + kt * 16 + quad * 4) = pk;
      }
    __asm__ volatile("s_waitcnt lgkmcnt(0)" ::: "memory");  // wave-local P RAW

    // ---- O^T += V^T * P^T ----
#pragma unroll
    for (int ks = 0; ks < 4; ++ks) {
      bf16x8 Pf[2];
#pragma unroll
      for (int qt = 0; qt < 2; ++qt)
        Pf[qt] = *(bf16x8*)(Pw + (qt * 16 + col) * P_STRIDE + ks * 32 + quad * 8);
#pragma unroll
      for (int ft = 0; ft < 4; ++ft) {
        bf16x8 Vf = *(bf16x8*)(Vsh + (ft * 16 + col) * V_STRIDE + ks * 32 + quad * 8);
#pragma unroll
        for (int qt = 0; qt < 2; ++qt)
          accO[ft][qt] = __builtin_amdgcn_mfma_f32_16x16x32_bf16(Vf, Pf[qt], accO[ft][qt], 0, 0, 0);
      }
    }
  }

  // ---- epilogue: O = O^T / l, float4 stores ----
  float rl[2] = {1.0f / l_run[0], 1.0f / l_run[1]};
#pragma unroll
  for (int ft = 0; ft < 4; ++ft)
#pragma unroll
    for (int qt = 0; qt < 2; ++qt) {
      const int qrow = qtile * M_TILE + wave * QW + qt * 16 + col;
      float* dst = Og + (size_t)(b * S_ + qrow) * D_ + h * DH + ft * 16 + quad * 4;
      floatx4 o = accO[ft][qt] * rl[qt];
      *(floatx4*)dst = o;
    }
}

extern "C" void kernel_launch(void* const* d_in, const int* in_sizes, int n_in,
                              void* d_out, int out_size, void* d_ws, size_t ws_size,
                              hipStream_t stream) {
  const float* Q = (const float*)d_in[0];
  const float* K = (const float*)d_in[1];
  const float* V = (const float*)d_in[2];
  float* O = (float*)d_out;
  dim3 grid(B_ * H_ * (S_ / M_TILE));   // 512 blocks; bid%32 = head -> XCD-stable
  dim3 block(256);
  hipLaunchKernelGGL(attn_fwd, grid, block, 0, stream, Q, K, V, O);
}